// Round 4
// baseline (185.209 us; speedup 1.0000x reference)
//
#include <hip/hip_runtime.h>

// SpikingReadoutLayer:
//   h2[b,t,o] = sum_h in[b,t,h] * W[h,o]
//   flt' = a*flt + h_t ; out' = b*out + flt (OLD flt); out_rec[b,0,:]=0
//
// Kernel 1: one wave per (b, chunk of 125 rows). lane = 16c + o; c-group
// covers h in [64c, 64c+64). W fragment (64 floats) pinned in VGPRs (fence
// prevents rematerialization -- R1's failure). Per row: 16 float4 loads
// (4x 64B lines/instr, fully consumed via L1 across 4 instrs), 64 FMA,
// xor16/xor32 butterfly => all lanes hold h_t for their o; scan carried in
// registers. 1-row-deep prefetch double-buffer hides HBM latency.
// Kernel 2: closed-form affine fixup across chunks (A^k analytic).

constexpr int B_ = 128, T_ = 2000, H_ = 256, O_ = 16;
constexpr int TOUT = T_ + 1;                 // 2001
constexpr int CHUNKS = 16, CL = 125;         // 16*125 = 2000
constexpr float ALPHA = 0.95f, BETA = 0.9f;
constexpr float INV_AB = 20.0f;              // 1/(ALPHA-BETA)
constexpr float L2A = -0.07400058144377693f; // log2(0.95)
constexpr float L2B = -0.15200309344504997f; // log2(0.90)

__global__ __launch_bounds__(256, 2)
void h2scan_kernel(const float* __restrict__ in, const float* __restrict__ W,
                   float* __restrict__ out, float* __restrict__ ws) {
    const int wid  = blockIdx.x * 4 + (threadIdx.x >> 6);   // 0..2047
    const int lane = threadIdx.x & 63;
    const int c = lane >> 4, o = lane & 15;
    const int b = wid >> 4;       // CHUNKS = 16
    const int j = wid & 15;

    // Per-lane W fragment: wr[q] = W[64c+q][o]. Must live in VGPRs.
    float wr[64];
    {
        const float* Wp = W + (size_t)(c * 64) * O_ + o;
#pragma unroll
        for (int q = 0; q < 64; ++q) wr[q] = Wp[(size_t)q * O_];
    }
    asm volatile("" ::: "memory");   // pin: no sink/remat of W loads into loop

    const float* ip = in + ((size_t)b * T_ + (size_t)j * CL) * H_ + c * 64;
    float* op = out + ((size_t)b * TOUT + (size_t)j * CL + 1) * O_ + o;

    if (j == 0 && lane < 16) out[(size_t)b * TOUT * O_ + o] = 0.f; // out_rec[b,0,o]

    float4 xa[8], xb[8], pa[8], pb[8];
    {
        const float4* rp = (const float4*)ip;
#pragma unroll
        for (int q = 0; q < 8; ++q) xa[q] = rp[q];
#pragma unroll
        for (int q = 0; q < 8; ++q) xb[q] = rp[8 + q];
    }

    float flt = 0.f, oo = 0.f;
    for (int t = 0; t < CL; ++t) {
        if (t + 1 < CL) {   // prefetch next row (16 float4 in flight)
            const float4* rp = (const float4*)(ip + (size_t)(t + 1) * H_);
#pragma unroll
            for (int q = 0; q < 8; ++q) pa[q] = rp[q];
#pragma unroll
            for (int q = 0; q < 8; ++q) pb[q] = rp[8 + q];
        }
        float p0 = 0.f, p1 = 0.f, p2 = 0.f, p3 = 0.f;
#pragma unroll
        for (int q = 0; q < 8; ++q) {
            p0 = fmaf(xa[q].x, wr[4 * q + 0], p0);
            p1 = fmaf(xa[q].y, wr[4 * q + 1], p1);
            p2 = fmaf(xa[q].z, wr[4 * q + 2], p2);
            p3 = fmaf(xa[q].w, wr[4 * q + 3], p3);
        }
#pragma unroll
        for (int q = 0; q < 8; ++q) {
            p0 = fmaf(xb[q].x, wr[32 + 4 * q + 0], p0);
            p1 = fmaf(xb[q].y, wr[32 + 4 * q + 1], p1);
            p2 = fmaf(xb[q].z, wr[32 + 4 * q + 2], p2);
            p3 = fmaf(xb[q].w, wr[32 + 4 * q + 3], p3);
        }
        float h = (p0 + p1) + (p2 + p3);
        h += __shfl_xor(h, 16);
        h += __shfl_xor(h, 32);              // all lanes: h_t for their o

        const float no = fmaf(BETA, oo, flt);  // uses OLD flt
        flt = fmaf(ALPHA, flt, h);
        oo = no;
        if (lane < 16) op[(size_t)t * O_] = no;  // 64B coalesced row store

#pragma unroll
        for (int q = 0; q < 8; ++q) { xa[q] = pa[q]; xb[q] = pb[q]; }
    }

    if (lane < 16) {   // chunk-final local state
        float* wp = ws + ((size_t)(b * O_ + o) * CHUNKS + j) * 2;
        wp[0] = flt;
        wp[1] = oo;
    }
}

// Kernel 2: chunk j>0 start state s0 = sum_{m<j} A^{CL*(j-1-m)} * sigma_m,
// A^k = [[a^k,0],[g_k,b^k]], g_k=(a^k-b^k)/(a-b); then
// out[b, j*CL+tloc+1, o] += g_{tloc+1}*f0 + b^{tloc+1}*o0.
__global__ __launch_bounds__(256)
void fixup_kernel(float* __restrict__ out, const float* __restrict__ ws) {
    const int blk = blockIdx.x;
    const int b = blk >> 4;       // CHUNKS = 16
    const int j = blk & 15;
    if (j == 0) return;

    __shared__ float f0s[O_], o0s[O_];
    const int tid = threadIdx.x;
    if (tid < O_) {
        const float* wp = ws + ((size_t)(b * O_ + tid) * CHUNKS) * 2;
        float f = 0.f, oacc = 0.f;
        for (int m = 0; m < j; ++m) {      // <= 15 terms
            const float k  = (float)((j - 1 - m) * CL);
            const float a  = exp2f(k * L2A);
            const float bb = exp2f(k * L2B);
            const float g  = (a - bb) * INV_AB;
            const float sf = wp[m * 2 + 0];
            const float so = wp[m * 2 + 1];
            f    = fmaf(a, sf, f);
            oacc = fmaf(g, sf, fmaf(bb, so, oacc));
        }
        f0s[tid] = f;
        o0s[tid] = oacc;
    }
    __syncthreads();

    const size_t rowbase = ((size_t)b * TOUT + (size_t)j * CL + 1) * O_;
    for (int e = tid; e < CL * O_; e += 256) {    // 2000 elems, 8 iters
        const int tloc = e >> 4;
        const int o = e & 15;
        const float k  = (float)(tloc + 1);
        const float a  = exp2f(k * L2A);
        const float bb = exp2f(k * L2B);
        const float g  = (a - bb) * INV_AB;
        out[rowbase + e] = fmaf(g, f0s[o], fmaf(bb, o0s[o], out[rowbase + e]));
    }
}

extern "C" void kernel_launch(void* const* d_in, const int* in_sizes, int n_in,
                              void* d_out, int out_size, void* d_ws, size_t ws_size,
                              hipStream_t stream) {
    const float* in = (const float*)d_in[0];   // [B, T, H]
    const float* W  = (const float*)d_in[1];   // [H, O]
    float* out = (float*)d_out;                // [B, T+1, O]
    float* ws  = (float*)d_ws;                 // 128*16*16*2*4 B = 256 KiB

    h2scan_kernel<<<dim3((B_ * CHUNKS) / 4), dim3(256), 0, stream>>>(in, W, out, ws);
    fixup_kernel<<<dim3(B_ * CHUNKS), dim3(256), 0, stream>>>(out, ws);
}

// Round 5
// 73.361 us; speedup vs baseline: 2.5246x; 2.5246x over previous
//
#include <hip/hip_runtime.h>

// SpikingReadoutLayer:
//   h2[b,t,o] = sum_h in[b,t,h] * W[h,o]
//   flt' = a*flt + h_t ; out' = b*out + flt (OLD flt); out_rec[b,0,:]=0
//
// Kernel 1: one block per (b, chunk of 250 rows). Input staged through LDS
// in 8 h-chunks of 32 with COALESCED global loads (8 rows x 128B per wave
// instr, all lines fully consumed); compute is thread-per-row from LDS
// (stride-36 padding -> conflict-free b128 reads); W read via wave-uniform
// addresses (scalarizes to s_load / L1-resident). Then block-local scan in
// the same LDS buffer and coalesced writeback. Chunk-final states -> ws.
// Kernel 2: closed-form affine fixup across chunks (A^k analytic).

constexpr int B_ = 128, T_ = 2000, H_ = 256, O_ = 16;
constexpr int TOUT = T_ + 1;                 // 2001
constexpr int CHUNKS = 8, CL = 250;          // 8*250 = 2000
constexpr int HC = 32;                       // h per stage chunk (8 chunks)
constexpr int SSTR = 36;                     // stage row stride (floats), 144B: 16B-aligned, bank-spread ok
constexpr int PAD = 20;                      // scan tile row stride (floats)
constexpr float ALPHA = 0.95f, BETA = 0.9f;
constexpr float INV_AB = 20.0f;              // 1/(ALPHA-BETA)
constexpr float L2A = -0.07400058144377693f; // log2(0.95)
constexpr float L2B = -0.15200309344504997f; // log2(0.90)

__global__ __launch_bounds__(256, 4)
void h2scan_kernel(const float* __restrict__ in, const float* __restrict__ W,
                   float* __restrict__ out, float* __restrict__ ws) {
    __shared__ float buf[CL * SSTR];   // 36 KB; stage buffer, reused as scan tile
    const int tid = threadIdx.x;
    const int b = blockIdx.x >> 3;     // CHUNKS = 8
    const int j = blockIdx.x & 7;

    const float* inb = in + ((size_t)b * T_ + (size_t)j * CL) * H_;
    const int row = (tid < CL) ? tid : 0;   // clamp: uniform control flow

    float acc[16];
#pragma unroll
    for (int o = 0; o < 16; ++o) acc[o] = 0.f;

    for (int c = 0; c < CHUNKS; ++c) {
        // ---- stage chunk [CL rows x 32 h] into LDS, coalesced ----
        // flat float4 index f: row r = f>>3, quad q = f&7.
        // Wave instr covers 8 rows x 128 consecutive bytes each.
#pragma unroll
        for (int it = 0; it < 8; ++it) {
            const int f = it * 256 + tid;
            if (f < CL * 8) {
                const int r = f >> 3, q = f & 7;
                const float4 v =
                    *(const float4*)(inb + (size_t)r * H_ + c * HC + 4 * q);
                *(float4*)&buf[r * SSTR + 4 * q] = v;
            }
        }
        __syncthreads();

        // ---- compute: thread-per-row, 32 h x 16 o FMAs ----
        float x[HC];
#pragma unroll
        for (int q = 0; q < 8; ++q) {
            const float4 v = *(const float4*)&buf[row * SSTR + 4 * q];
            x[4 * q + 0] = v.x; x[4 * q + 1] = v.y;
            x[4 * q + 2] = v.z; x[4 * q + 3] = v.w;
        }
        const float* __restrict__ Wc = W + c * HC * O_;  // wave-uniform reads
#pragma unroll
        for (int hh = 0; hh < HC; ++hh) {
            const float xv = x[hh];
#pragma unroll
            for (int o = 0; o < 16; ++o)
                acc[o] = fmaf(xv, Wc[hh * 16 + o], acc[o]);
        }
        __syncthreads();
    }

    // ---- acc -> scan tile (reuses buf; all stage reads are done) ----
    if (tid < CL) {
        float4* tp = (float4*)&buf[tid * PAD];
        tp[0] = make_float4(acc[0],  acc[1],  acc[2],  acc[3]);
        tp[1] = make_float4(acc[4],  acc[5],  acc[6],  acc[7]);
        tp[2] = make_float4(acc[8],  acc[9],  acc[10], acc[11]);
        tp[3] = make_float4(acc[12], acc[13], acc[14], acc[15]);
    }
    __syncthreads();

    // ---- 16 serial chains down the columns (conflict-free, PAD=20) ----
    if (tid < O_) {
        float flt = 0.f, oo = 0.f;
        float* col = &buf[tid];
#pragma unroll 5
        for (int t = 0; t < CL; ++t) {
            const float h = col[t * PAD];
            const float no = fmaf(BETA, oo, flt);  // uses OLD flt
            flt = fmaf(ALPHA, flt, h);
            col[t * PAD] = no;
            oo = no;
        }
        float* wp = ws + ((size_t)(b * O_ + tid) * CHUNKS + j) * 2;
        wp[0] = flt;
        wp[1] = oo;
        if (j == 0) out[(size_t)b * TOUT * O_ + tid] = 0.f;  // out_rec[b,0,o]
    }
    __syncthreads();

    // ---- coalesced writeback ----
    const size_t obase = ((size_t)b * TOUT + (size_t)j * CL + 1) * O_;
    for (int e = tid; e < CL * O_; e += 256)
        out[obase + e] = buf[(e >> 4) * PAD + (e & 15)];
}

// Kernel 2: chunk j>0 start state s0 = sum_{m<j} A^{CL*(j-1-m)} * sigma_m,
// A^k = [[a^k,0],[g_k,b^k]], g_k=(a^k-b^k)/(a-b); then
// out[b, j*CL+tloc+1, o] += g_{tloc+1}*f0 + b^{tloc+1}*o0.
__global__ __launch_bounds__(256)
void fixup_kernel(float* __restrict__ out, const float* __restrict__ ws) {
    const int blk = blockIdx.x;
    const int b = blk >> 3;
    const int j = blk & 7;
    if (j == 0) return;

    __shared__ float f0s[O_], o0s[O_];
    const int tid = threadIdx.x;
    if (tid < O_) {
        const float* wp = ws + ((size_t)(b * O_ + tid) * CHUNKS) * 2;
        float f = 0.f, oacc = 0.f;
        for (int m = 0; m < j; ++m) {      // <= 7 terms
            const float k  = (float)((j - 1 - m) * CL);
            const float a  = exp2f(k * L2A);
            const float bb = exp2f(k * L2B);
            const float g  = (a - bb) * INV_AB;
            const float sf = wp[m * 2 + 0];
            const float so = wp[m * 2 + 1];
            f    = fmaf(a, sf, f);
            oacc = fmaf(g, sf, fmaf(bb, so, oacc));
        }
        f0s[tid] = f;
        o0s[tid] = oacc;
    }
    __syncthreads();

    const size_t rowbase = ((size_t)b * TOUT + (size_t)j * CL + 1) * O_;
    for (int e = tid; e < CL * O_; e += 256) {
        const int tloc = e >> 4;
        const int o = e & 15;
        const float k  = (float)(tloc + 1);
        const float a  = exp2f(k * L2A);
        const float bb = exp2f(k * L2B);
        const float g  = (a - bb) * INV_AB;
        out[rowbase + e] = fmaf(g, f0s[o], fmaf(bb, o0s[o], out[rowbase + e]));
    }
}

extern "C" void kernel_launch(void* const* d_in, const int* in_sizes, int n_in,
                              void* d_out, int out_size, void* d_ws, size_t ws_size,
                              hipStream_t stream) {
    const float* in = (const float*)d_in[0];   // [B, T, H]
    const float* W  = (const float*)d_in[1];   // [H, O]
    float* out = (float*)d_out;                // [B, T+1, O]
    float* ws  = (float*)d_ws;                 // 128*16*8*2*4 B = 128 KiB

    h2scan_kernel<<<dim3(B_ * CHUNKS), dim3(256), 0, stream>>>(in, W, out, ws);
    fixup_kernel<<<dim3(B_ * CHUNKS), dim3(256), 0, stream>>>(out, ws);
}